// Round 12
// baseline (316.561 us; speedup 1.0000x reference)
//
#include <hip/hip_runtime.h>
#include <math.h>

// LeCun LCN, fused single kernel, radius-5 truncated Gaussian (taps d>=6 have
// total weight 1.2e-8 -- numerically invisible vs the 4.9e-2 threshold).
//
// mean     = gauss11x11 * x          (separable, zero-pad SAME)
// centered = x - mean
// var      = gauss11x11 * centered^2 (zero-pad SAME)
// out      = centered / (sqrt(var) + 1e-4) * mask
//
// R1:  TH=16 lost 14% (occupancy bought with +25% halo work).
// R4:  sliding register windows = -21% (245->194us).
// R7:  conv-2 vblur->hblur swap = -6% (194->182us).
// R8:  s1 ring -> 4 blocks/CU: occ 26->34, only -2%. Occupancy not the lever.
// R11: TH=64 strip: -10% work, -42% barriers -> FLAT (182us). Not work-bound,
//      not barrier-count-bound. Diagnosis: lock-step barriers keep all waves
//      in the same phase -> correlated dependency stalls; VALU 36 / LDS ~25 /
//      HBM 14 all unsaturated.
// R12: BREAK LOCK-STEP for conv-2. After P2b, b2 is read-only and conv-2 is
//      row-local: vc row r needs b2 rows r..r+10 only; final hblur needs vc
//      row r only. No cross-wave dependency -> each wave free-runs its 8
//      output rows (2 chunks x 4 rows) with a PRIVATE vc scratch (s1h rows
//      4w..4w+3; s1h dead after P2b). Wave-local s_waitcnt lgkmcnt(0)
//      (DS ops of a wave complete in order) + asm memory fences replace
//      3 block barriers. Barriers 7 -> 4; waves de-phase -> LDS/VALU mix.
//
//  s1h ring[48][132]: hblur(x), image rows h0-10..h0+73 streamed in 2 fills
//  b2      [74][132]: centered = x - vblur(s1)   (b2 row br = image h0-5+br)
//  free-run: per wave, vc chunk -> vscr[4][132]; hblur(vc)=var + epilogue

#define TW 32
#define TH 64
#define S1W 132          // LDS row stride (126 cols used + pad)
#define S1R 48           // s1 ring rows
#define B2R 74           // TH + 10
#define NT  512

__global__ __launch_bounds__(NT, 4)
void lecun_lcn_kernel(const float* __restrict__ x,
                      const float* __restrict__ mask,
                      float* __restrict__ out)
{
    __shared__ float s1h[S1R * S1W];   // 25,344 B (scratch for vc after P2b)
    __shared__ float b2[B2R * S1W];    // 39,072 B  (total 64,416 -> 2 blocks/CU)

    const int tid = threadIdx.x;
    const int w0  = blockIdx.x * TW;
    const int h0  = blockIdx.y * TH;
    const int bi  = blockIdx.z;
    const int fc0 = 3 * w0 - 15;      // flat col of s1/b2/vc index 0

    // 1D Gaussian (std=1), taps 0..5, normalized by the full 19-tap sum.
    const float K[6] = {
        3.9894227826685783e-01f,
        2.4197072322439816e-01f,
        5.3990966224238430e-02f,
        4.4318483882270000e-03f,
        1.3383022504889000e-04f,
        1.4867195067806000e-06f
    };

    const float* xb = x + (size_t)bi * 512 * 1536;

    // ---- P1 task: hblur image row (h0-10+ss) into ring slot, 16-col run ----
    auto p1_task = [&](int ss, int slot, int run) {
        const int h = h0 - 10 + ss;
        float* dst = &s1h[slot * S1W + run * 16];
        if ((unsigned)h >= 512u) {
            float4 z = make_float4(0.f, 0.f, 0.f, 0.f);
            ((float4*)dst)[0] = z; ((float4*)dst)[1] = z;
            ((float4*)dst)[2] = z; ((float4*)dst)[3] = z;
            return;
        }
        const float* xrow = xb + (size_t)h * 1536;
        const int gc0 = fc0 + run * 16;    // first output flat col
        const int a   = gc0 - 17;          // window start; gc0%4==1 -> a%4==0
        float w[48];
        if (a >= 0 && a <= 1536 - 48) {
            const float4* p = (const float4*)(xrow + a);
            #pragma unroll
            for (int q = 0; q < 12; ++q) {
                float4 v = p[q];
                w[4*q+0] = v.x; w[4*q+1] = v.y; w[4*q+2] = v.z; w[4*q+3] = v.w;
            }
        } else {
            #pragma unroll
            for (int i = 0; i < 48; ++i) {
                int j = a + i;
                w[i] = ((unsigned)j < 1536u) ? xrow[j] : 0.0f;
            }
        }
        float v1[16];
        #pragma unroll
        for (int i = 0; i < 16; ++i) {
            const int ci = 17 + i;
            float acc = K[0] * w[ci];
            #pragma unroll
            for (int d = 1; d <= 5; ++d)
                acc = fmaf(K[d], w[ci - 3*d] + w[ci + 3*d], acc);
            v1[i] = acc;
        }
        ((float4*)dst)[0] = make_float4(v1[0],  v1[1],  v1[2],  v1[3]);
        ((float4*)dst)[1] = make_float4(v1[4],  v1[5],  v1[6],  v1[7]);
        ((float4*)dst)[2] = make_float4(v1[8],  v1[9],  v1[10], v1[11]);
        ((float4*)dst)[3] = make_float4(v1[12], v1[13], v1[14], v1[15]);
    };

    // ---- P2: produce cnt b2 rows from rb; sliding register window ----------
    auto p2_run = [&](int rb, int cnt) {
        const int quad = tid & 31;
        const int c4   = quad * 4;
        const int gcb  = fc0 + c4;
        const bool cv0 = (unsigned)(gcb + 0) < 1536u;
        const bool cv1 = (unsigned)(gcb + 1) < 1536u;
        const bool cv2 = (unsigned)(gcb + 2) < 1536u;
        const bool cv3 = (unsigned)(gcb + 3) < 1536u;
        float4 w[13];                      // s1 rows rb..rb+cnt+9 (ring)
        #pragma unroll
        for (int k = 0; k < 13; ++k) {
            if (k < cnt + 10) {
                const int ss = rb + k;
                const int sl = (ss >= S1R) ? ss - S1R : ss;
                w[k] = *(const float4*)&s1h[sl * S1W + c4];
            }
        }
        #pragma unroll
        for (int j = 0; j < 3; ++j) {
            if (j < cnt) {
                const int br = rb + j;
                const int h = h0 - 5 + br;
                float4* dst = (float4*)&b2[br * S1W + c4];
                if ((unsigned)h >= 512u) {
                    *dst = make_float4(0.f, 0.f, 0.f, 0.f);
                } else {
                    float m0 = K[0] * w[j+5].x, m1 = K[0] * w[j+5].y;
                    float m2 = K[0] * w[j+5].z, m3 = K[0] * w[j+5].w;
                    #pragma unroll
                    for (int d = 1; d <= 5; ++d) {
                        float4 aa = w[j + 5 - d];
                        float4 bb = w[j + 5 + d];
                        m0 = fmaf(K[d], aa.x + bb.x, m0);
                        m1 = fmaf(K[d], aa.y + bb.y, m1);
                        m2 = fmaf(K[d], aa.z + bb.z, m2);
                        m3 = fmaf(K[d], aa.w + bb.w, m3);
                    }
                    const float* xrow = xb + (size_t)h * 1536;
                    // out-of-image cols must be exact 0 (zero-pad of conv-2)
                    float c0 = cv0 ? (xrow[gcb + 0] - m0) : 0.0f;
                    float c1 = cv1 ? (xrow[gcb + 1] - m1) : 0.0f;
                    float c2 = cv2 ? (xrow[gcb + 2] - m2) : 0.0f;
                    float c3 = cv3 ? (xrow[gcb + 3] - m3) : 0.0f;
                    *dst = make_float4(c0, c1, c2, c3);
                }
            }
        }
    };

    // ---------------- schedule: staged P1/P2 (block barriers) ---------------
    // P1a: ss 0..47 -> slots 0..47 (384 tasks)
    if (tid < 384) p1_task(tid >> 3, tid >> 3, tid & 7);
    __syncthreads();

    // P2a: b2 rows 0..37 (needs ss 0..47)
    {
        const int rt  = tid >> 5;
        const int cnt = (rt < 6) ? 3 : 2;
        const int rb  = (rt < 6) ? 3 * rt : 18 + 2 * (rt - 6);
        p2_run(rb, cnt);
    }
    __syncthreads();

    // P1b: ss 48..83 -> slots 0..35 (288 tasks; slots 36..47 keep ss 36..47)
    if (tid < 288) p1_task(48 + (tid >> 3), tid >> 3, tid & 7);
    __syncthreads();

    // P2b: b2 rows 38..73 (needs ss 38..83: slots 38..47 old + 0..35 new)
    {
        const int rt  = tid >> 5;
        const int cnt = (rt < 4) ? 3 : 2;
        const int rb  = (rt < 4) ? 38 + 3 * rt : 50 + 2 * (rt - 4);
        p2_run(rb, cnt);
    }
    __syncthreads();

    // ---------------- free-run conv-2: per-wave, NO block barriers ----------
    // b2 is read-only from here. Wave wv owns output rows 8wv..8wv+7 in two
    // 4-row chunks; private vc scratch = s1h rows 4wv..4wv+3 (s1h is dead).
    // Cross-lane visibility within the wave: DS ops of one wave complete in
    // order; s_waitcnt lgkmcnt(0) + memory clobber fences compiler reorder.
    {
        const int wv   = tid >> 6;          // 0..7
        const int lane = tid & 63;
        float* vscr = &s1h[(wv * 4) * S1W];
        const int q   = lane & 31;          // P3 role: col quad
        const int hf  = lane >> 5;          // P3 role: row pair 0/1
        const int c4  = q * 4;
        const int rr  = (lane >> 3) & 3;    // P4 role (lanes<32): row 0..3
        const int run = lane & 7;           // P4 role: 12-col run 0..7
        const int tc0 = run * 12;

        #pragma unroll
        for (int ck = 0; ck < 2; ++ck) {
            const int r0 = wv * 8 + ck * 4;      // output rows r0..r0+3
            // ---- P3 chunk: vc rows r0..r0+3 -> vscr rows 0..3 ----
            {
                float4 w[12];                    // b2sq rows r0+2hf .. +11
                #pragma unroll
                for (int k = 0; k < 12; ++k) {
                    float4 t = *(const float4*)&b2[(r0 + 2*hf + k) * S1W + c4];
                    w[k] = make_float4(t.x*t.x, t.y*t.y, t.z*t.z, t.w*t.w);
                }
                #pragma unroll
                for (int j2 = 0; j2 < 2; ++j2) {
                    float s0  = K[0]*w[j2+5].x, s1v = K[0]*w[j2+5].y;
                    float s2v = K[0]*w[j2+5].z, s3  = K[0]*w[j2+5].w;
                    #pragma unroll
                    for (int d = 1; d <= 5; ++d) {
                        float4 aa = w[j2+5-d], bb = w[j2+5+d];
                        s0  = fmaf(K[d], aa.x+bb.x, s0);
                        s1v = fmaf(K[d], aa.y+bb.y, s1v);
                        s2v = fmaf(K[d], aa.z+bb.z, s2v);
                        s3  = fmaf(K[d], aa.w+bb.w, s3);
                    }
                    *(float4*)&vscr[(2*hf + j2) * S1W + c4] =
                        make_float4(s0, s1v, s2v, s3);
                }
            }
            // drain this wave's vscr writes before any lane reads them
            asm volatile("s_waitcnt lgkmcnt(0)" ::: "memory");
            // ---- P4 chunk: hblur(vscr)=var + epilogue (lanes < 32) ----
            if (lane < 32) {
                float w[44];                     // vscr[rr][tc0 .. tc0+43]
                #pragma unroll
                for (int qq = 0; qq < 11; ++qq) {
                    float4 v = *(const float4*)&vscr[rr * S1W + tc0 + 4*qq];
                    w[4*qq+0]=v.x; w[4*qq+1]=v.y; w[4*qq+2]=v.z; w[4*qq+3]=v.w;
                }
                float cw[16];                    // centered, b2 row r0+rr+5
                #pragma unroll
                for (int qq = 0; qq < 4; ++qq) {
                    float4 v = *(const float4*)&b2[(r0 + rr + 5) * S1W + tc0 + 12 + 4*qq];
                    cw[4*qq+0]=v.x; cw[4*qq+1]=v.y; cw[4*qq+2]=v.z; cw[4*qq+3]=v.w;
                }
                const int h = h0 + r0 + rr;
                const size_t rowoff = (size_t)(bi * 512 + h);
                const float* mrow = mask + rowoff * 512 + w0 + 4 * run;
                float mv[4];
                #pragma unroll
                for (int k2 = 0; k2 < 4; ++k2) mv[k2] = mrow[k2];
                float o[12];
                #pragma unroll
                for (int j = 0; j < 12; ++j) {
                    const int ci = 15 + j;
                    float var = K[0] * w[ci];
                    #pragma unroll
                    for (int d = 1; d <= 5; ++d)
                        var = fmaf(K[d], w[ci - 3*d] + w[ci + 3*d], var);
                    o[j] = cw[j + 3] * __builtin_amdgcn_rcpf(sqrtf(var) + 1e-4f) * mv[j / 3];
                }
                float* orow = &out[rowoff * 1536 + 3 * w0 + tc0];
                ((float4*)orow)[0] = make_float4(o[0], o[1], o[2],  o[3]);
                ((float4*)orow)[1] = make_float4(o[4], o[5], o[6],  o[7]);
                ((float4*)orow)[2] = make_float4(o[8], o[9], o[10], o[11]);
            }
            // keep chunk-1 vscr reads ordered before chunk-2 vscr writes
            asm volatile("" ::: "memory");
        }
    }
}

extern "C" void kernel_launch(void* const* d_in, const int* in_sizes, int n_in,
                              void* d_out, int out_size, void* d_ws, size_t ws_size,
                              hipStream_t stream) {
    const float* x0   = (const float*)d_in[0];
    const float* mask = (const float*)d_in[1];
    float* out = (float*)d_out;

    dim3 grid(512 / TW, 512 / TH, 32);   // (16, 8, 32) = 4096 blocks
    dim3 block(NT);
    lecun_lcn_kernel<<<grid, block, 0, stream>>>(x0, mask, out);
}

// Round 13
// 279.501 us; speedup vs baseline: 1.1326x; 1.1326x over previous
//
#include <hip/hip_runtime.h>
#include <math.h>

// LeCun LCN, fused single kernel, radius-5 truncated Gaussian (taps d>=6 have
// total weight 1.2e-8 -- numerically invisible vs the 4.9e-2 threshold).
//
// mean     = gauss11x11 * x          (separable, zero-pad SAME)
// centered = x - mean
// var      = gauss11x11 * centered^2 (zero-pad SAME)
// out      = centered / (sqrt(var) + 1e-4) * mask
//
// Ledger: R4 sliding windows -21%; R7 conv-2 swap -6%; R8 ring/4 blocks -2%
// (178us, BEST); R11 TH=64 -10% work -> FLAT; R12 free-run +30% VALU issue ->
// +4% WORSE (VALUBusy 35->47). Model: kernel tracks ISSUED INSTRUCTIONS.
// R13: R8 base + ALIGNED HALO fc0 = 3*w0-16 (was -15). Staged width 128.
//  - P2 center-x: ONE aligned float4 (was 4 misaligned scalar dwords) and the
//    4 per-element ternaries collapse to one all-or-nothing test (1536%4==0
//    => a 4-col group is fully in/out of image).
//  - P4 centered: exactly 3 aligned b128 at tc0+16 (was 4 + offset-3 extract).
//  - P1 window start gc0-16 stays 12 aligned dwordx4 (ci shifts 17->16).
//  - mask: one aligned float4.
//
//  s1h ring[32][132]: hblur(x), image rows h0-10..h0+41 in 2 fills
//  b2      [42][132]: centered = x - vblur(s1)
//  vc (overlays s1h) [32][132]: vblur(b2^2)
//  P4: hblur(vc)=var + epilogue, 256 tasks (row, 12-col run)

#define TW 32
#define TH 32
#define S1W 132          // LDS row stride (128 cols used + 4 pad; 132%32=4)
#define S1R 32           // s1 ring rows (slot = ss & 31)
#define B2R 42           // TH + 10
#define NT  256

__global__ __launch_bounds__(NT, 4)
void lecun_lcn_kernel(const float* __restrict__ x,
                      const float* __restrict__ mask,
                      float* __restrict__ out)
{
    __shared__ float s1h[S1R * S1W];   // 16,896 B (reused as vc[32][132])
    __shared__ float b2[B2R * S1W];    // 22,176 B  (total 39,072 -> 4 blocks/CU)

    const int tid = threadIdx.x;
    const int w0  = blockIdx.x * TW;
    const int h0  = blockIdx.y * TH;
    const int bi  = blockIdx.z;
    const int fc0 = 3 * w0 - 16;      // ALIGNED: flat col of staged idx 0

    // 1D Gaussian (std=1), taps 0..5, normalized by the full 19-tap sum.
    const float K[6] = {
        3.9894227826685783e-01f,
        2.4197072322439816e-01f,
        5.3990966224238430e-02f,
        4.4318483882270000e-03f,
        1.3383022504889000e-04f,
        1.4867195067806000e-06f
    };

    const float* xb = x + (size_t)bi * 512 * 1536;

    // ---- P1 task: hblur image row (h0-10+ss) into ring slot, 16-col run ----
    auto p1_task = [&](int ss, int slot, int run) {
        const int h = h0 - 10 + ss;
        float* dst = &s1h[slot * S1W + run * 16];
        if ((unsigned)h >= 512u) {
            float4 z = make_float4(0.f, 0.f, 0.f, 0.f);
            ((float4*)dst)[0] = z; ((float4*)dst)[1] = z;
            ((float4*)dst)[2] = z; ((float4*)dst)[3] = z;
            return;
        }
        const float* xrow = xb + (size_t)h * 1536;
        const int gc0 = fc0 + run * 16;    // first output flat col, %4 == 0
        const int a   = gc0 - 16;          // aligned window start
        float w[48];                       // x[a .. a+47]; taps use w[1..46]
        if (a >= 0 && a <= 1536 - 48) {
            const float4* p = (const float4*)(xrow + a);
            #pragma unroll
            for (int q = 0; q < 12; ++q) {
                float4 v = p[q];
                w[4*q+0] = v.x; w[4*q+1] = v.y; w[4*q+2] = v.z; w[4*q+3] = v.w;
            }
        } else {
            #pragma unroll
            for (int i = 0; i < 48; ++i) {
                int j = a + i;
                w[i] = ((unsigned)j < 1536u) ? xrow[j] : 0.0f;
            }
        }
        float v1[16];
        #pragma unroll
        for (int i = 0; i < 16; ++i) {
            const int ci = 16 + i;         // center x[gc0+i] at w[16+i]
            float acc = K[0] * w[ci];
            #pragma unroll
            for (int d = 1; d <= 5; ++d)
                acc = fmaf(K[d], w[ci - 3*d] + w[ci + 3*d], acc);
            v1[i] = acc;
        }
        ((float4*)dst)[0] = make_float4(v1[0],  v1[1],  v1[2],  v1[3]);
        ((float4*)dst)[1] = make_float4(v1[4],  v1[5],  v1[6],  v1[7]);
        ((float4*)dst)[2] = make_float4(v1[8],  v1[9],  v1[10], v1[11]);
        ((float4*)dst)[3] = make_float4(v1[12], v1[13], v1[14], v1[15]);
    };

    // ---- P2: produce cnt b2 rows from rb; sliding register window ----------
    auto p2_run = [&](int rb, int cnt) {
        const int q   = tid & 31;
        const int c4  = q * 4;
        const int gcb = fc0 + c4;          // %4 == 0
        // 1536%4==0 and gcb%4==0 => the 4-col group is fully in or fully out
        const bool cvAll = (gcb >= 0) && (gcb <= 1536 - 4);
        float4 w[13];                      // s1 rows rb..rb+cnt+9 (ring)
        #pragma unroll
        for (int k = 0; k < 13; ++k) {
            if (k < cnt + 10)
                w[k] = *(const float4*)&s1h[((rb + k) & 31) * S1W + c4];
        }
        #pragma unroll
        for (int j = 0; j < 3; ++j) {
            if (j < cnt) {
                const int br = rb + j;
                const int h = h0 - 5 + br;
                float4* dst = (float4*)&b2[br * S1W + c4];
                if ((unsigned)h >= 512u || !cvAll) {
                    *dst = make_float4(0.f, 0.f, 0.f, 0.f);
                } else {
                    float m0 = K[0] * w[j+5].x, m1 = K[0] * w[j+5].y;
                    float m2 = K[0] * w[j+5].z, m3 = K[0] * w[j+5].w;
                    #pragma unroll
                    for (int d = 1; d <= 5; ++d) {
                        float4 aa = w[j + 5 - d];
                        float4 bb = w[j + 5 + d];
                        m0 = fmaf(K[d], aa.x + bb.x, m0);
                        m1 = fmaf(K[d], aa.y + bb.y, m1);
                        m2 = fmaf(K[d], aa.z + bb.z, m2);
                        m3 = fmaf(K[d], aa.w + bb.w, m3);
                    }
                    const float* xrow = xb + (size_t)h * 1536;
                    float4 xv = *(const float4*)(xrow + gcb);  // ONE aligned load
                    *dst = make_float4(xv.x - m0, xv.y - m1,
                                       xv.z - m2, xv.w - m3);
                }
            }
        }
    };

    // ---------------- schedule ----------------------------------------------
    // P1a: ss 0..31 -> slots 0..31 (256 tasks)
    p1_task(tid >> 3, tid >> 3, tid & 7);
    __syncthreads();

    // P2a: b2 rows 0..21 (needs ss 0..31)
    {
        const int rt  = tid >> 5;
        const int cnt = (rt < 6) ? 3 : 2;
        const int rb  = (rt < 6) ? 3 * rt : 18 + 2 * (rt - 6);
        p2_run(rb, cnt);
    }
    __syncthreads();

    // P1b: ss 32..51 -> slots 0..19 (160 tasks; slots 20..31 keep ss 20..31)
    if (tid < 160) p1_task(32 + (tid >> 3), tid >> 3, tid & 7);
    __syncthreads();

    // P2b: b2 rows 22..41 (needs ss 22..51: slots 22..31 old + 0..19 new)
    {
        const int rt  = tid >> 5;
        const int cnt = (rt < 4) ? 3 : 2;
        const int rb  = (rt < 4) ? 22 + 3 * rt : 34 + 2 * (rt - 4);
        p2_run(rb, cnt);
    }
    __syncthreads();

    // ---------------- P3: vblur(b2^2) -> vc (reuse s1h) ---------------------
    float* vc = s1h;                       // 32 x 132
    {
        const int q  = tid & 31;
        const int rt = tid >> 5;
        const int r0 = rt * 4;
        const int c4 = q * 4;
        float4 w[14];                      // b2sq rows r0..r0+13
        #pragma unroll
        for (int k = 0; k < 14; ++k) {
            float4 t = *(const float4*)&b2[(r0 + k) * S1W + c4];
            w[k] = make_float4(t.x*t.x, t.y*t.y, t.z*t.z, t.w*t.w);
        }
        #pragma unroll
        for (int j = 0; j < 4; ++j) {
            float s0 = K[0] * w[j+5].x, s1v = K[0] * w[j+5].y;
            float s2v = K[0] * w[j+5].z, s3 = K[0] * w[j+5].w;
            #pragma unroll
            for (int d = 1; d <= 5; ++d) {
                float4 aa = w[j + 5 - d];
                float4 bb = w[j + 5 + d];
                s0  = fmaf(K[d], aa.x + bb.x, s0);
                s1v = fmaf(K[d], aa.y + bb.y, s1v);
                s2v = fmaf(K[d], aa.z + bb.z, s2v);
                s3  = fmaf(K[d], aa.w + bb.w, s3);
            }
            *(float4*)&vc[(r0 + j) * S1W + c4] = make_float4(s0, s1v, s2v, s3);
        }
    }
    __syncthreads();

    // ---------------- P4: hblur(vc)=var; epilogue ---------------------------
    // 256 tasks: (row r = tid>>3, run = tid&7), 12 flat cols per task.
    // Output flat col = 3*w0 + 12*run + j  <->  staged idx = 16 + 12*run + j.
    {
        const int r    = tid >> 3;
        const int run  = tid & 7;
        const int tc0  = run * 12;
        float w[44];                       // vc[r][tc0 .. tc0+43]; taps [tc0+1, tc0+42]
        #pragma unroll
        for (int qq = 0; qq < 11; ++qq) {
            float4 v = *(const float4*)&vc[r * S1W + tc0 + 4*qq];
            w[4*qq+0] = v.x; w[4*qq+1] = v.y; w[4*qq+2] = v.z; w[4*qq+3] = v.w;
        }
        // centered: b2 row r+5, staged idx tc0+16 .. tc0+27 = 3 ALIGNED b128
        float cw[12];
        #pragma unroll
        for (int qq = 0; qq < 3; ++qq) {
            float4 v = *(const float4*)&b2[(r + 5) * S1W + tc0 + 16 + 4*qq];
            cw[4*qq+0] = v.x; cw[4*qq+1] = v.y; cw[4*qq+2] = v.z; cw[4*qq+3] = v.w;
        }
        const int h = h0 + r;
        const size_t rowoff = (size_t)(bi * 512 + h);
        float4 mv4 = *(const float4*)(mask + rowoff * 512 + w0 + 4 * run);
        float mv[4] = { mv4.x, mv4.y, mv4.z, mv4.w };
        float o[12];
        #pragma unroll
        for (int j = 0; j < 12; ++j) {
            const int ci = 16 + j;         // center in w
            float var = K[0] * w[ci];
            #pragma unroll
            for (int d = 1; d <= 5; ++d)
                var = fmaf(K[d], w[ci - 3*d] + w[ci + 3*d], var);
            o[j] = cw[j] * __builtin_amdgcn_rcpf(sqrtf(var) + 1e-4f) * mv[j / 3];
        }
        float* orow = &out[rowoff * 1536 + 3 * w0 + tc0];
        ((float4*)orow)[0] = make_float4(o[0], o[1], o[2],  o[3]);
        ((float4*)orow)[1] = make_float4(o[4], o[5], o[6],  o[7]);
        ((float4*)orow)[2] = make_float4(o[8], o[9], o[10], o[11]);
    }
}

extern "C" void kernel_launch(void* const* d_in, const int* in_sizes, int n_in,
                              void* d_out, int out_size, void* d_ws, size_t ws_size,
                              hipStream_t stream) {
    const float* x0   = (const float*)d_in[0];
    const float* mask = (const float*)d_in[1];
    float* out = (float*)d_out;

    dim3 grid(512 / TW, 512 / TH, 32);   // (16, 16, 32) = 8192 blocks
    dim3 block(NT);
    lecun_lcn_kernel<<<grid, block, 0, stream>>>(x0, mask, out);
}